// Round 4
// baseline (122.625 us; speedup 1.0000x reference)
//
#include <hip/hip_runtime.h>

// Problem constants: B=2, L=2048, H=8, D=64, window=32, stride=64
#define Bc 2
#define Lc 2048
#define Hc 8
#define Dc 64
#define TL 16                 // rows per block
#define NT (Lc / TL)          // 128 tiles
#define RHD (Hc * Dc)         // 512 floats between consecutive s rows
#define SP1 65                // stride+1
#define SCALE 0.125f          // 1/sqrt(64)

// DPP-based add of a permuted copy: pure VALU, no DS traffic.
template <int CTRL>
__device__ __forceinline__ float dpp_add(float x) {
    int p = __builtin_amdgcn_update_dpp(0, __float_as_int(x), CTRL, 0xF, 0xF, true);
    return x + __int_as_float(p);
}
// 16-lane-row sum (verified R3/R4): xor1, xor2, half-mirror, mirror.
__device__ __forceinline__ float row16_sum(float x) {
    x = dpp_add<0xB1>(x);
    x = dpp_add<0x4E>(x);
    x = dpp_add<0x141>(x);
    x = dpp_add<0x140>(x);
    return x;
}

// ---------------------------------------------------------------------------
// Kernel 1: per-(b,h) tile sums of V -> partials[bh][t][d]
// ---------------------------------------------------------------------------
__global__ __launch_bounds__(256)
void dozer_chunk_sum(const float* __restrict__ V, float* __restrict__ partials) {
    const int bh = blockIdx.x;
    const int t  = blockIdx.y;
    const int b  = bh >> 3;
    const int h  = bh & 7;
    const int g  = threadIdx.x >> 6;
    const int d  = threadIdx.x & 63;
    const float* Vbh = V + (size_t)b * Lc * RHD + h * Dc;
    const int l0 = t * TL;
    float s = 0.f;
    for (int r = g; r < TL; r += 4)
        s += Vbh[(size_t)(l0 + r) * RHD + d];
    __shared__ float red[4][64];
    red[g][d] = s;
    __syncthreads();
    if (g == 0)
        partials[((size_t)bh * NT + t) * 64 + d] =
            red[0][d] + red[1][d] + red[2][d] + red[3][d];
}

// ---------------------------------------------------------------------------
// Kernel 2: fused main kernel. Block = (bh, tile of 16 rows), 4 waves,
// 4 rows/wave. Lane layout: p = lane>>4 (slot 0..3), dd = lane&15 (d-quad).
//
// Latency plan (R4):
//  - Q software-pipeline: row rr+1's Q load issues at the TOP of iteration
//    rr (consumed next iteration); row 0's Q hoisted before the prefix
//    phase. Removes the ~600-900cy cold-HBM Q stall per row.
//  - Far loop: depth-4 rotating prefetch; 4 prologue load-pairs issued
//    before the band phase (band compute covers them). No launch_bounds
//    occupancy pin -> compiler free to hold all buffers without spilling.
//  - Prefix partials read as float4 in <=2 predicated batches of 4.
// LDS: Kband 8K + Vband 8K + Ptile 4K = 20480 B.
// ---------------------------------------------------------------------------
__global__ __launch_bounds__(256)
void dozer_main(const float* __restrict__ Q, const float* __restrict__ K,
                const float* __restrict__ V, const float* __restrict__ partials,
                float* __restrict__ out) {
    const int bh   = blockIdx.x;
    const int t    = (NT - 1) - blockIdx.y;   // heavy tiles first
    const int b    = bh >> 3;
    const int h    = bh & 7;
    const int tid  = threadIdx.x;
    const int wave = tid >> 6;
    const int lane = tid & 63;
    const int l0   = t * TL;
    const int p    = lane >> 4;
    const int dd   = lane & 15;

    const float* Qbh = Q + (size_t)b * Lc * RHD + h * Dc;
    const float* Kbh = K + (size_t)b * Lc * RHD + h * Dc;
    const float* Vbh = V + (size_t)b * Lc * RHD + h * Dc;

    __shared__ float Kband[32][64];
    __shared__ float Vband[32][64];
    __shared__ float Ptile[TL][64];
    // redf aliases Kband rows 0..19 (5120 B < 8192 B): prefix scratch, fully
    // consumed before the band staging writes clobber it.
    float* redf = &Kband[0][0];

    // ---- 0. hoist Q row for rr=0 (prefix phase covers its latency) ----
    float4 qcur = *(const float4*)&Qbh[(size_t)(l0 + 4 * wave) * RHD + dd * 4];

    // ---- 1. prefix phase ----
    {
        const int cc0 = 4 * wave + p;   // slot id 0..15
        float4 pa = make_float4(0.f, 0.f, 0.f, 0.f);
        if (partials) {
            const float* pb = partials + (size_t)bh * NT * 64 + dd * 4;
            if (t > 0) {    // batch 1: tiles cc0+{0,16,32,48} (always in-bounds)
                const float4 f0 = *(const float4*)(pb + (size_t)(cc0     ) * 64);
                const float4 f1 = *(const float4*)(pb + (size_t)(cc0 + 16) * 64);
                const float4 f2 = *(const float4*)(pb + (size_t)(cc0 + 32) * 64);
                const float4 f3 = *(const float4*)(pb + (size_t)(cc0 + 48) * 64);
                if (cc0      < t) { pa.x += f0.x; pa.y += f0.y; pa.z += f0.z; pa.w += f0.w; }
                if (cc0 + 16 < t) { pa.x += f1.x; pa.y += f1.y; pa.z += f1.z; pa.w += f1.w; }
                if (cc0 + 32 < t) { pa.x += f2.x; pa.y += f2.y; pa.z += f2.z; pa.w += f2.w; }
                if (cc0 + 48 < t) { pa.x += f3.x; pa.y += f3.y; pa.z += f3.z; pa.w += f3.w; }
            }
            if (t > 64) {   // batch 2: tiles cc0+{64,80,96,112}
                const float4 f4 = *(const float4*)(pb + (size_t)(cc0 +  64) * 64);
                const float4 f5 = *(const float4*)(pb + (size_t)(cc0 +  80) * 64);
                const float4 f6 = *(const float4*)(pb + (size_t)(cc0 +  96) * 64);
                const float4 f7 = *(const float4*)(pb + (size_t)(cc0 + 112) * 64);
                if (cc0 +  64 < t) { pa.x += f4.x; pa.y += f4.y; pa.z += f4.z; pa.w += f4.w; }
                if (cc0 +  80 < t) { pa.x += f5.x; pa.y += f5.y; pa.z += f5.z; pa.w += f5.w; }
                if (cc0 +  96 < t) { pa.x += f6.x; pa.y += f6.y; pa.z += f6.z; pa.w += f6.w; }
                if (cc0 + 112 < t) { pa.x += f7.x; pa.y += f7.y; pa.z += f7.z; pa.w += f7.w; }
            }
        } else {
            // no-workspace fallback: sum V rows directly, slot-strided, float4
            for (int s = cc0; s < l0; s += 16) {
                const float4 v4 = *(const float4*)(Vbh + (size_t)s * RHD + dd * 4);
                pa.x += v4.x; pa.y += v4.y; pa.z += v4.z; pa.w += v4.w;
            }
        }
        *(float4*)&redf[cc0 * 64 + dd * 4] = pa;

        // V carry rows (scalar-d layout)
        const int d = lane;
        const float* vr = Vbh + (size_t)(l0 + 4 * wave) * RHD + d;
        const float x0 = vr[0];
        const float x1 = vr[RHD];
        const float x2 = vr[2 * RHD];
        const float x3 = vr[3 * RHD];
        const float s0 = x0, s1 = s0 + x1, s2 = s1 + x2, s3 = s2 + x3;
        redf[(16 + wave) * 64 + d] = s3;
        __syncthreads();
        float base = 0.f;
        #pragma unroll
        for (int r2 = 0; r2 < 16; ++r2) base += redf[r2 * 64 + d];
        if (wave > 0) base += redf[16 * 64 + d];
        if (wave > 1) base += redf[17 * 64 + d];
        if (wave > 2) base += redf[18 * 64 + d];
        Ptile[4 * wave + 0][d] = base + s0;
        Ptile[4 * wave + 1][d] = base + s1;
        Ptile[4 * wave + 2][d] = base + s2;
        Ptile[4 * wave + 3][d] = base + s3;
        __syncthreads();   // everyone done with redf before staging clobbers it
    }

    // ---- 2. stage band rows [l0-16, l0+15] of K and V into LDS ----
    {
        const int si = tid >> 4;            // 0..15
        const int c4 = (tid & 15) * 4;
        int j0 = l0 - 16 + si; if (j0 < 0) j0 = 0;   // t=0 garbage masked later
        const int j1 = l0 + si;
        *(float4*)&Kband[si][c4]      = *(const float4*)(Kbh + (size_t)j0 * RHD + c4);
        *(float4*)&Vband[si][c4]      = *(const float4*)(Vbh + (size_t)j0 * RHD + c4);
        *(float4*)&Kband[si + 16][c4] = *(const float4*)(Kbh + (size_t)j1 * RHD + c4);
        *(float4*)&Vband[si + 16][c4] = *(const float4*)(Vbh + (size_t)j1 * RHD + c4);
        __syncthreads();
    }

    qcur.x *= SCALE; qcur.y *= SCALE; qcur.z *= SCALE; qcur.w *= SCALE;

    for (int rr = 0; rr < 4; ++rr) {
        const int r = wave * 4 + rr;
        const int l = l0 + r;
        const int nk   = l / SP1;            // far offsets 65f, f = 1..nk
        const int nfar = (nk + 3) >> 2;      // far iterations (4 slots each)

        // ---- issue next row's Q load now; consumed next iteration ----
        float4 qnext = make_float4(0.f, 0.f, 0.f, 0.f);
        if (rr < 3)
            qnext = *(const float4*)&Qbh[(size_t)(l + 1) * RHD + dd * 4];

        const float4 q4 = qcur;

        float4 acc = make_float4(0.f, 0.f, 0.f, 0.f);
        float  den = 0.f;

        auto farload = [&](float4& k4, float4& v4, int m) {
            const int f = 1 + p + 4 * m;
            int j = l - SP1 * f; if (j < 0) j = 0;
            k4 = *(const float4*)(Kbh + (size_t)j * RHD + dd * 4);
            v4 = *(const float4*)(Vbh + (size_t)j * RHD + dd * 4);
        };
        auto farstep = [&](const float4& k4, const float4& v4, int m) {
            const int f = 1 + p + 4 * m;
            const bool ok = (f <= nk);
            float dot = q4.x * k4.x + q4.y * k4.y + q4.z * k4.z + q4.w * k4.w;
            dot = row16_sum(dot);
            float w = __expf(dot) - 1.f;
            w = ok ? w : 0.f;
            acc.x += w * v4.x; acc.y += w * v4.y;
            acc.z += w * v4.z; acc.w += w * v4.w;
            den += w;
        };

        // far prologue: issue up to 4 load-pairs NOW; band phase covers them
        float4 k0, v0, k1, v1, k2, v2, k3, v3;
        if (nfar > 0) farload(k0, v0, 0);
        if (nfar > 1) farload(k1, v1, 1);
        if (nfar > 2) farload(k2, v2, 2);
        if (nfar > 3) farload(k3, v3, 3);

        // ---- band from LDS: offsets 0..15 ----
        #pragma unroll
        for (int it = 0; it < 4; ++it) {
            const int off = p + 4 * it;
            const int idx = r + 16 - off;          // in [1, 31]
            const bool ok = (off <= l);
            const float4 k4 = *(const float4*)&Kband[idx][dd * 4];
            const float4 v4 = *(const float4*)&Vband[idx][dd * 4];
            float dot = q4.x * k4.x + q4.y * k4.y + q4.z * k4.z + q4.w * k4.w;
            dot = row16_sum(dot);
            float w = __expf(dot) - 1.f;
            w = ok ? w : 0.f;
            acc.x += w * v4.x; acc.y += w * v4.y;
            acc.z += w * v4.z; acc.w += w * v4.w;
            den += w;
        }
        {   // band edge offset 16 (slot p==0 only), idx = r >= 0
            const bool ok = (p == 0) && (l >= 16);
            const float4 k4 = *(const float4*)&Kband[r][dd * 4];
            const float4 v4 = *(const float4*)&Vband[r][dd * 4];
            float dot = q4.x * k4.x + q4.y * k4.y + q4.z * k4.z + q4.w * k4.w;
            dot = row16_sum(dot);
            float w = __expf(dot) - 1.f;
            w = ok ? w : 0.f;
            acc.x += w * v4.x; acc.y += w * v4.y;
            acc.z += w * v4.z; acc.w += w * v4.w;
            den += w;
        }

        // ---- far loop: depth-4 rotating prefetch, unrolled by 4 ----
        int m = 0;
        for (; m + 4 <= nfar; m += 4) {
            farstep(k0, v0, m    ); if (m + 4 < nfar) farload(k0, v0, m + 4);
            farstep(k1, v1, m + 1); if (m + 5 < nfar) farload(k1, v1, m + 5);
            farstep(k2, v2, m + 2); if (m + 6 < nfar) farload(k2, v2, m + 6);
            farstep(k3, v3, m + 3); if (m + 7 < nfar) farload(k3, v3, m + 7);
        }
        if (m     < nfar) farstep(k0, v0, m);
        if (m + 1 < nfar) farstep(k1, v1, m + 1);
        if (m + 2 < nfar) farstep(k2, v2, m + 2);
        // (m+3 < nfar impossible: loop exits with nfar - m <= 3)

        // ---- combine across the 4 position groups (xor 16, 32) ----
        acc.x += __shfl_xor(acc.x, 16, 64); acc.x += __shfl_xor(acc.x, 32, 64);
        acc.y += __shfl_xor(acc.y, 16, 64); acc.y += __shfl_xor(acc.y, 32, 64);
        acc.z += __shfl_xor(acc.z, 16, 64); acc.z += __shfl_xor(acc.z, 32, 64);
        acc.w += __shfl_xor(acc.w, 16, 64); acc.w += __shfl_xor(acc.w, 32, 64);
        den   += __shfl_xor(den, 16, 64);   den   += __shfl_xor(den, 32, 64);

        const float inv = 1.f / ((float)(l + 1) + den);
        if (p == 0) {
            const float4 P4 = *(const float4*)&Ptile[r][dd * 4];
            float4 o;
            o.x = (P4.x + acc.x) * inv;
            o.y = (P4.y + acc.y) * inv;
            o.z = (P4.z + acc.z) * inv;
            o.w = (P4.w + acc.w) * inv;
            *(float4*)&out[((size_t)(b * Lc + l) * Hc + h) * Dc + dd * 4] = o;
        }

        // ---- rotate the Q pipeline ----
        if (rr < 3) {
            qcur = qnext;
            qcur.x *= SCALE; qcur.y *= SCALE; qcur.z *= SCALE; qcur.w *= SCALE;
        }
    }
}

// ---------------------------------------------------------------------------
extern "C" void kernel_launch(void* const* d_in, const int* in_sizes, int n_in,
                              void* d_out, int out_size, void* d_ws, size_t ws_size,
                              hipStream_t stream) {
    // inputs: 0=x (unused), 1=queries, 2=keys, 3=values, 4=attn_mask (analytic)
    const float* Q = (const float*)d_in[1];
    const float* K = (const float*)d_in[2];
    const float* V = (const float*)d_in[3];
    float* out = (float*)d_out;

    const size_t np = (size_t)Bc * Hc * NT * 64 * sizeof(float);  // 512 KB
    float* partials = (ws_size >= np && d_ws != nullptr) ? (float*)d_ws : nullptr;

    dim3 grid(Bc * Hc, NT);   // bh fastest: balances per-CU tile mix
    if (partials)
        dozer_chunk_sum<<<grid, 256, 0, stream>>>(V, partials);
    dozer_main<<<grid, 256, 0, stream>>>(Q, K, V, partials, out);
}

// Round 6
// 122.349 us; speedup vs baseline: 1.0023x; 1.0023x over previous
//
#include <hip/hip_runtime.h>

// Problem constants: B=2, L=2048, H=8, D=64, window=32, stride=64
#define Bc 2
#define Lc 2048
#define Hc 8
#define Dc 64
#define TL 16                 // rows per block
#define NT (Lc / TL)          // 128 tiles
#define RHD (Hc * Dc)         // 512 floats between consecutive s rows
#define SP1 65                // stride+1
#define SCALE 0.125f          // 1/sqrt(64)

// DPP-based add of a permuted copy: pure VALU, no DS traffic.
template <int CTRL>
__device__ __forceinline__ float dpp_add(float x) {
    int p = __builtin_amdgcn_update_dpp(0, __float_as_int(x), CTRL, 0xF, 0xF, true);
    return x + __int_as_float(p);
}
// 16-lane-row sum (verified R3/R4): xor1, xor2, half-mirror, mirror.
__device__ __forceinline__ float row16_sum(float x) {
    x = dpp_add<0xB1>(x);
    x = dpp_add<0x4E>(x);
    x = dpp_add<0x141>(x);
    x = dpp_add<0x140>(x);
    return x;
}

// ---------------------------------------------------------------------------
// Kernel 1: per-(b,h) tile sums of V -> partials[bh][t][d]
// ---------------------------------------------------------------------------
__global__ __launch_bounds__(256)
void dozer_chunk_sum(const float* __restrict__ V, float* __restrict__ partials) {
    const int bh = blockIdx.x;
    const int t  = blockIdx.y;
    const int b  = bh >> 3;
    const int h  = bh & 7;
    const int g  = threadIdx.x >> 6;
    const int d  = threadIdx.x & 63;
    const float* Vbh = V + (size_t)b * Lc * RHD + h * Dc;
    const int l0 = t * TL;
    float s = 0.f;
    for (int r = g; r < TL; r += 4)
        s += Vbh[(size_t)(l0 + r) * RHD + d];
    __shared__ float red[4][64];
    red[g][d] = s;
    __syncthreads();
    if (g == 0)
        partials[((size_t)bh * NT + t) * 64 + d] =
            red[0][d] + red[1][d] + red[2][d] + red[3][d];
}

// ---------------------------------------------------------------------------
// Kernel 2: main kernel — EXACT R0 internals (verified 115.7 us), with ONE
// change: XCD-locality block swizzle (T1). Linear grid n in [0,2048);
//   xcd = n & 7, slot = n >> 3, bh = 2*xcd + (slot & 1), t = NT-1-(slot>>1).
// Under round-robin block->XCD dispatch (bid % 8), each XCD owns exactly
// 2 bh => 2 MB of K+V, fits its 4 MiB L2 => far loads become L2 hits
// instead of L3 (~200 vs ~400+ cyc). Heavy tiles still first. If the
// dispatch mapping ever changes this only affects locality, not
// correctness (mapping is bijective: xcd=bh>>1, slot=2*(NT-1-t)+(bh&1),
// n=8*slot+xcd).
// LDS: Kband 8K + Vband 8K + Ptile 4K = 20480 B -> 8 blocks/CU (160 KiB).
// ---------------------------------------------------------------------------
__global__ __launch_bounds__(256)
void dozer_main(const float* __restrict__ Q, const float* __restrict__ K,
                const float* __restrict__ V, const float* __restrict__ partials,
                float* __restrict__ out) {
    const int n    = blockIdx.x;
    const int xcd  = n & 7;
    const int slot = n >> 3;
    const int bh   = 2 * xcd + (slot & 1);    // 2 bh per XCD -> L2-resident K/V
    const int t    = (NT - 1) - (slot >> 1);  // heavy tiles first
    const int b    = bh >> 3;
    const int h    = bh & 7;
    const int tid  = threadIdx.x;
    const int wave = tid >> 6;
    const int lane = tid & 63;
    const int l0   = t * TL;

    const float* Qbh = Q + (size_t)b * Lc * RHD + h * Dc;
    const float* Kbh = K + (size_t)b * Lc * RHD + h * Dc;
    const float* Vbh = V + (size_t)b * Lc * RHD + h * Dc;

    __shared__ float Kband[32][64];
    __shared__ float Vband[32][64];
    __shared__ float Ptile[TL][64];
    // red aliases the first 2 KB of Kband: used only in the prefix phase,
    // fully consumed before staging overwrites it.
    float (*red)[64] = (float(*)[64])Kband;

    // ---- prefix phase: wave w owns rows 4w..4w+3 ----
    {
        const int d = lane;
        float pbase = 0.f;
        if (partials) {
            const float* pb = partials + (size_t)bh * NT * 64;
            #pragma unroll 4
            for (int c = wave; c < t; c += 4)
                pbase += pb[(size_t)c * 64 + d];
        } else {
            for (int s = wave; s < l0; s += 4)
                pbase += Vbh[(size_t)s * RHD + d];
        }
        const float* vr = Vbh + (size_t)(l0 + 4 * wave) * RHD + d;
        const float x0 = vr[0];
        const float x1 = vr[RHD];
        const float x2 = vr[2 * RHD];
        const float x3 = vr[3 * RHD];
        const float s0 = x0, s1 = s0 + x1, s2 = s1 + x2, s3 = s2 + x3;
        red[wave][d]     = pbase;
        red[4 + wave][d] = s3;
        __syncthreads();
        float base = red[0][d] + red[1][d] + red[2][d] + red[3][d];
        if (wave > 0) base += red[4][d];
        if (wave > 1) base += red[5][d];
        if (wave > 2) base += red[6][d];
        Ptile[4 * wave + 0][d] = base + s0;
        Ptile[4 * wave + 1][d] = base + s1;
        Ptile[4 * wave + 2][d] = base + s2;
        Ptile[4 * wave + 3][d] = base + s3;
        __syncthreads();   // everyone done with red before staging clobbers it
    }

    // ---- stage band rows [l0-16, l0+15] of K and V into LDS ----
    {
        const int i  = tid >> 4;            // 0..15
        const int c4 = (tid & 15) * 4;
        #pragma unroll
        for (int rnd = 0; rnd < 2; ++rnd) {
            const int ii = i + 16 * rnd;    // 0..31
            int j = l0 - 16 + ii; if (j < 0) j = 0;   // t=0 garbage rows masked later
            *(float4*)&Kband[ii][c4] = *(const float4*)(Kbh + (size_t)j * RHD + c4);
            *(float4*)&Vband[ii][c4] = *(const float4*)(Vbh + (size_t)j * RHD + c4);
        }
        __syncthreads();
    }

    const int p  = lane >> 4;
    const int dd = lane & 15;

    for (int rr = 0; rr < 4; ++rr) {
        const int r = wave * 4 + rr;
        const int l = l0 + r;
        const int nk   = l / SP1;            // far offsets 65f, f = 1..nk
        const int nfar = (nk + 3) >> 2;      // far iterations (4 slots each)

        float4 q4 = *(const float4*)&Qbh[(size_t)l * RHD + dd * 4];
        q4.x *= SCALE; q4.y *= SCALE; q4.z *= SCALE; q4.w *= SCALE;

        float4 acc = make_float4(0.f, 0.f, 0.f, 0.f);
        float  den = 0.f;

        auto farload = [&](float4& k4, float4& v4, int m) {
            const int f = 1 + p + 4 * m;
            int j = l - SP1 * f; if (j < 0) j = 0;
            k4 = *(const float4*)(Kbh + (size_t)j * RHD + dd * 4);
            v4 = *(const float4*)(Vbh + (size_t)j * RHD + dd * 4);
        };
        auto farstep = [&](const float4& k4, const float4& v4, int m) {
            const int f = 1 + p + 4 * m;
            const bool ok = (f <= nk);
            float dot = q4.x * k4.x + q4.y * k4.y + q4.z * k4.z + q4.w * k4.w;
            dot = row16_sum(dot);
            float w = __expf(dot) - 1.f;
            w = ok ? w : 0.f;
            acc.x += w * v4.x; acc.y += w * v4.y;
            acc.z += w * v4.z; acc.w += w * v4.w;
            den += w;
        };

        // far prologue: issue global loads now; band phase below covers latency
        float4 kA = make_float4(0.f,0.f,0.f,0.f), vA = kA, kB = kA, vB = kA;
        if (nfar > 0) farload(kA, vA, 0);
        if (nfar > 1) farload(kB, vB, 1);

        // ---- band from LDS: offsets 0..15 ----
        #pragma unroll
        for (int it = 0; it < 4; ++it) {
            const int off = p + 4 * it;
            const int idx = r + 16 - off;          // in [1, 31]
            const bool ok = (off <= l);
            const float4 k4 = *(const float4*)&Kband[idx][dd * 4];
            const float4 v4 = *(const float4*)&Vband[idx][dd * 4];
            float dot = q4.x * k4.x + q4.y * k4.y + q4.z * k4.z + q4.w * k4.w;
            dot = row16_sum(dot);
            float w = __expf(dot) - 1.f;
            w = ok ? w : 0.f;
            acc.x += w * v4.x; acc.y += w * v4.y;
            acc.z += w * v4.z; acc.w += w * v4.w;
            den += w;
        }
        {   // band edge offset 16 (slot p==0 only), idx = r >= 0
            const bool ok = (p == 0) && (l >= 16);
            const float4 k4 = *(const float4*)&Kband[r][dd * 4];
            const float4 v4 = *(const float4*)&Vband[r][dd * 4];
            float dot = q4.x * k4.x + q4.y * k4.y + q4.z * k4.z + q4.w * k4.w;
            dot = row16_sum(dot);
            float w = __expf(dot) - 1.f;
            w = ok ? w : 0.f;
            acc.x += w * v4.x; acc.y += w * v4.y;
            acc.z += w * v4.z; acc.w += w * v4.w;
            den += w;
        }

        // ---- far loop: depth-2 rotating prefetch ----
        int m = 0;
        for (; m + 1 < nfar; m += 2) {
            farstep(kA, vA, m);
            if (m + 2 < nfar) farload(kA, vA, m + 2);
            farstep(kB, vB, m + 1);
            if (m + 3 < nfar) farload(kB, vB, m + 3);
        }
        if (m < nfar) farstep(kA, vA, m);

        // ---- combine across the 4 position groups (xor 16, 32) ----
        acc.x += __shfl_xor(acc.x, 16, 64); acc.x += __shfl_xor(acc.x, 32, 64);
        acc.y += __shfl_xor(acc.y, 16, 64); acc.y += __shfl_xor(acc.y, 32, 64);
        acc.z += __shfl_xor(acc.z, 16, 64); acc.z += __shfl_xor(acc.z, 32, 64);
        acc.w += __shfl_xor(acc.w, 16, 64); acc.w += __shfl_xor(acc.w, 32, 64);
        den   += __shfl_xor(den, 16, 64);   den   += __shfl_xor(den, 32, 64);

        const float inv = 1.f / ((float)(l + 1) + den);
        if (p == 0) {
            const float4 P4 = *(const float4*)&Ptile[r][dd * 4];
            float4 o;
            o.x = (P4.x + acc.x) * inv;
            o.y = (P4.y + acc.y) * inv;
            o.z = (P4.z + acc.z) * inv;
            o.w = (P4.w + acc.w) * inv;
            *(float4*)&out[((size_t)(b * Lc + l) * Hc + h) * Dc + dd * 4] = o;
        }
    }
}

// ---------------------------------------------------------------------------
extern "C" void kernel_launch(void* const* d_in, const int* in_sizes, int n_in,
                              void* d_out, int out_size, void* d_ws, size_t ws_size,
                              hipStream_t stream) {
    // inputs: 0=x (unused), 1=queries, 2=keys, 3=values, 4=attn_mask (analytic)
    const float* Q = (const float*)d_in[1];
    const float* K = (const float*)d_in[2];
    const float* V = (const float*)d_in[3];
    float* out = (float*)d_out;

    const size_t need = (size_t)Bc * Hc * NT * 64 * sizeof(float);  // 512 KB
    float* partials = (ws_size >= need && d_ws != nullptr) ? (float*)d_ws : nullptr;

    if (partials)
        dozer_chunk_sum<<<dim3(Bc * Hc, NT), 256, 0, stream>>>(V, partials);
    // linear grid with XCD-locality swizzle (see dozer_main header comment)
    dozer_main<<<dim3(Bc * Hc * NT), 256, 0, stream>>>(Q, K, V, partials, out);
}